// Round 2
// baseline (89557.880 us; speedup 1.0000x reference)
//
#include <hip/hip_runtime.h>
#include <math.h>

// Problem constants
constexpr int Bb = 64, Tt = 500, Ee = 256, Aa = 128, Dd = 400;
constexpr int STEPS = 500, Rr = 5;

// ---------------------------------------------------------------------------
// Pre-kernel: enc_proj[b,t,a] = sum_k enc_feat[b,t,k] * W_enc[k,a]
// ---------------------------------------------------------------------------
__global__ __launch_bounds__(512)
void k_encproj(const float* __restrict__ enc_feat,
               const float* __restrict__ W_enc,
               float* __restrict__ enc_proj) {
  __shared__ float sFeat[16][256];
  const int b = blockIdx.x, tg = blockIdx.y;
  const int t0 = tg * 16;
  const int tid = threadIdx.x;

  #pragma unroll
  for (int i = 0; i < 8; ++i) {
    int idx = tid + i * 512;
    int r = idx >> 8, c = idx & 255;
    int t = t0 + r;
    sFeat[r][c] = (t < Tt) ? enc_feat[((size_t)b * Tt + t) * Ee + c] : 0.0f;
  }
  __syncthreads();

  const int a = tid & 127, tl = tid >> 7;
  float acc0 = 0.f, acc1 = 0.f, acc2 = 0.f, acc3 = 0.f;
  #pragma unroll 4
  for (int k = 0; k < Ee; ++k) {
    float w = W_enc[k * Aa + a];
    acc0 = fmaf(sFeat[tl][k],      w, acc0);
    acc1 = fmaf(sFeat[tl + 4][k],  w, acc1);
    acc2 = fmaf(sFeat[tl + 8][k],  w, acc2);
    acc3 = fmaf(sFeat[tl + 12][k], w, acc3);
  }
  float accs[4] = {acc0, acc1, acc2, acc3};
  #pragma unroll
  for (int i = 0; i < 4; ++i) {
    int t = t0 + tl + 4 * i;
    if (t < Tt) enc_proj[((size_t)b * Tt + t) * Aa + a] = accs[i];
  }
}

// ---------------------------------------------------------------------------
// Helpers
// ---------------------------------------------------------------------------
template<int KS, int LDW>
__device__ __forceinline__ float4 dotq(const float* __restrict__ Wp,
                                       const float* __restrict__ xp) {
  float4 acc = {0.f, 0.f, 0.f, 0.f};
  #pragma unroll
  for (int k = 0; k < KS; ++k) {
    float xv = xp[k];
    float4 w = *(const float4*)(Wp + (size_t)k * LDW);
    acc.x = fmaf(xv, w.x, acc.x);
    acc.y = fmaf(xv, w.y, acc.y);
    acc.z = fmaf(xv, w.z, acc.z);
    acc.w = fmaf(xv, w.w, acc.w);
  }
  return acc;
}

__device__ __forceinline__ float sigmoid_acc(float x) {
  float e = __expf(-x);
  return 1.0f / (1.0f + e);
}

__device__ __forceinline__ float tanh_acc(float x) {
  float cx = fminf(9.5f, fmaxf(-9.5f, x));
  float e = __expf(2.0f * cx);
  return (e - 1.0f) / (e + 1.0f);
}

__device__ __forceinline__ float tanh_fast(float x) {   // hot path
  float cx = fminf(9.5f, fmaxf(-9.5f, x));
  float e = __expf(2.0f * cx);
  return (e - 1.0f) * __builtin_amdgcn_rcpf(e + 1.0f);
}

// ---------------------------------------------------------------------------
// Persistent decoder: 64 blocks x 1024 threads, 500 steps, state in LDS.
// ---------------------------------------------------------------------------
__global__ __launch_bounds__(1024)
void k_decoder(const float* __restrict__ enc_feat,
               const float* __restrict__ enc_proj,
               const float* __restrict__ W_p1, const float* __restrict__ b_p1,
               const float* __restrict__ W_p2, const float* __restrict__ b_p2,
               const float* __restrict__ W_ix, const float* __restrict__ W_ih,
               const float* __restrict__ b_ix, const float* __restrict__ b_ih,
               const float* __restrict__ W_dec, const float* __restrict__ b_attn,
               const float* __restrict__ v_attn,
               const float* __restrict__ W_out, const float* __restrict__ b_out,
               float* __restrict__ pred_out, float* __restrict__ attn_out) {
  __shared__ __align__(16) float sPred[400];
  __shared__ __align__(16) float sIn[384];    // [x(128) | ctx(256)] GRU input
  __shared__ __align__(16) float sL1[256];
  __shared__ __align__(16) float sCat[512];   // [h(256) | ctx(256)] W_out input
  __shared__ __align__(16) float sSd[128];
  __shared__ __align__(16) float sScore[512];
  __shared__ __align__(16) float sRaw[400];
  __shared__ __align__(16) float sTmp[4096];  // float4[1024] partials
  __shared__ float sRed[16];

  float* sH   = sCat;
  float* sCtx = sCat + 256;

  const int b = blockIdx.x;
  const int tid = threadIdx.x;
  const int lane = tid & 63, wid = tid >> 6;
  const int l4 = tid & 3;

  // ---- init state
  for (int i = tid; i < 400; i += 1024) sPred[i] = 0.f;
  if (tid < 256) { sH[tid] = 0.f; sCtx[tid] = 0.f; sIn[128 + tid] = 0.f; }

  // ---- preload constants into registers (latency off the critical path)
  float4 vq[8];
  #pragma unroll
  for (int i = 0; i < 8; ++i) vq[i] = *(const float4*)(v_attn + 4 * (l4 + 4 * i));

  float bP1 = 0.f, bR = 0.f, bZ = 0.f, bIN = 0.f, bHN = 0.f;
  if (tid < 256) {
    bP1 = b_p1[tid];
    bR  = b_ix[tid]       + b_ih[tid];
    bZ  = b_ix[256 + tid] + b_ih[256 + tid];
    bIN = b_ix[512 + tid];
    bHN = b_ih[512 + tid];
  }
  float bP2 = 0.f, bAt = 0.f;
  if (tid < 128) { bP2 = b_p2[tid]; bAt = b_attn[tid]; }
  float bOut = 0.f;
  if (tid < 400) bOut = b_out[tid];

  // ---- precompute per-thread GEMV geometry (constant across steps)
  // P1: W_p1 [400x256]: 64 quads x 16 slices, KS=25
  const float* p1W = W_p1 + 4 * (tid & 63) + (size_t)((tid >> 6) * 25) * 256;
  const float* p1x = sPred + (tid >> 6) * 25;
  // P2: W_p2 [256x128]: 32 quads x 32 slices, KS=8
  const float* p2W = W_p2 + 4 * (tid & 31) + (size_t)((tid >> 5) * 8) * 128;
  const float* p2x = sL1 + (tid >> 5) * 8;
  // P6: W_dec [256x128]: same geometry, x = h
  const float* p6W = W_dec + 4 * (tid & 31) + (size_t)((tid >> 5) * 8) * 128;
  const float* p6x = sH + (tid >> 5) * 8;
  // GRU fused: 1024 virtual cols = [512 combined r/z | 256 i_n | 256 h_n]
  //   A: tid<640  : q=tid&127 (cols 4q of 0..511), s=tid>>7 (5 slices of concat-640)
  //   B: 640..831 : i_n cols, W_ix[:,512+4q], 3 slices of 128
  //   C: 832..959 : h_n cols, W_ih[:,512+4q], 2 slices of 128
  const float* gW = W_ix;
  const float* gx = sIn;
  const bool gAct = tid < 960;
  if (tid < 640) {
    int q = tid & 127, s = tid >> 7;
    int kbase = s * 128;
    if (kbase < 384) { gW = W_ix + (size_t)kbase * 768 + 4 * q; gx = sIn + kbase; }
    else             { gW = W_ih + (size_t)(kbase - 384) * 768 + 4 * q; gx = sH + (kbase - 384); }
  } else if (tid < 832) {
    int u = tid - 640, q = u & 63, s = u >> 6;
    gW = W_ix + (size_t)(s * 128) * 768 + 512 + 4 * q; gx = sIn + s * 128;
  } else if (tid < 960) {
    int u = tid - 832, q = u & 63, s = u >> 6;
    gW = W_ih + (size_t)(s * 128) * 768 + 512 + 4 * q; gx = sH + s * 128;
  }
  // P10: W_out [512x400]: 100 quads x 8 slices, KS=64 (800 active)
  const int q10 = tid % 100, s10 = tid / 100;
  const float* p10W = W_out + 4 * q10 + (size_t)(64 * s10) * 400;
  const float* p10x = sCat + 64 * s10;
  // P9: ctx: 64 quads x 16 tt-slices
  const int e4i = tid & 63, sl9 = tid >> 6;
  const float* fb9 = enc_feat + (size_t)b * Tt * Ee + 4 * e4i;
  const int t9a = sl9 * 32;
  const int t9b = (t9a + 32 < Tt) ? t9a + 32 : Tt;

  __syncthreads();

  for (int t = 0; t < STEPS; ++t) {
    // ======== P1: l1 = relu(pred @ W_p1 + b_p1) ========
    { float4 a = dotq<25, 256>(p1W, p1x); *(float4*)&sTmp[tid * 4] = a; }
    __syncthreads();
    if (tid < 256) {
      float v = bP1;
      #pragma unroll
      for (int s = 0; s < 16; ++s) v += sTmp[(s * 64 + (tid >> 2)) * 4 + (tid & 3)];
      sL1[tid] = fmaxf(v, 0.f);
    }
    __syncthreads();

    // ======== P2: x = relu(l1 @ W_p2 + b_p2) -> sIn[0:128] ========
    { float4 a = dotq<8, 128>(p2W, p2x); *(float4*)&sTmp[tid * 4] = a; }
    __syncthreads();
    if (tid < 128) {
      float v = bP2;
      #pragma unroll
      for (int s = 0; s < 32; ++s) v += sTmp[(s * 32 + (tid >> 2)) * 4 + (tid & 3)];
      sIn[tid] = fmaxf(v, 0.f);
    }
    __syncthreads();

    // ======== GRU fused: all 6 GEMVs, one barrier, one combine ========
    if (gAct) { float4 a = dotq<128, 768>(gW, gx); *(float4*)&sTmp[tid * 4] = a; }
    __syncthreads();
    if (tid < 256) {
      const int qr = tid >> 2, el = tid & 3;
      float cr = bR, cz = bZ, vin = bIN, vhn = bHN;
      #pragma unroll
      for (int s = 0; s < 5; ++s) cr += sTmp[(s * 128 + qr) * 4 + el];
      #pragma unroll
      for (int s = 0; s < 5; ++s) cz += sTmp[(s * 128 + 64 + qr) * 4 + el];
      #pragma unroll
      for (int s = 0; s < 3; ++s) vin += sTmp[(640 + s * 64 + qr) * 4 + el];
      #pragma unroll
      for (int s = 0; s < 2; ++s) vhn += sTmp[(832 + s * 64 + qr) * 4 + el];
      float r = sigmoid_acc(cr);
      float z = sigmoid_acc(cz);
      float n = tanh_acc(vin + r * vhn);
      sH[tid] = (1.f - z) * n + z * sH[tid];
    }
    __syncthreads();

    // ======== P6: s_dec = h @ W_dec + b_attn ========
    { float4 a = dotq<8, 128>(p6W, p6x); *(float4*)&sTmp[tid * 4] = a; }
    __syncthreads();
    if (tid < 128) {
      float v = bAt;
      #pragma unroll
      for (int s = 0; s < 32; ++s) v += sTmp[(s * 32 + (tid >> 2)) * 4 + (tid & 3)];
      sSd[tid] = v;
    }
    __syncthreads();

    // ======== P7: scores[tt] = sum_a v[a]*tanh(enc_proj + s_dec) ========
    {
      float4 sdq[8];
      #pragma unroll
      for (int i = 0; i < 8; ++i) sdq[i] = *(const float4*)(sSd + 4 * (l4 + 4 * i));
      const int g = tid >> 2;
      #pragma unroll
      for (int p = 0; p < 2; ++p) {
        int tt = g + (p << 8);
        float acc = 0.f;
        if (tt < Tt) {
          const float4* ep = (const float4*)(enc_proj + ((size_t)b * Tt + tt) * Aa);
          #pragma unroll
          for (int i = 0; i < 8; ++i) {
            float4 e4 = ep[l4 + 4 * i];
            acc = fmaf(vq[i].x, tanh_fast(e4.x + sdq[i].x), acc);
            acc = fmaf(vq[i].y, tanh_fast(e4.y + sdq[i].y), acc);
            acc = fmaf(vq[i].z, tanh_fast(e4.z + sdq[i].z), acc);
            acc = fmaf(vq[i].w, tanh_fast(e4.w + sdq[i].w), acc);
          }
        }
        acc += __shfl_xor(acc, 1);
        acc += __shfl_xor(acc, 2);
        if (l4 == 0 && tt < Tt) sScore[tt] = acc;
      }
      __syncthreads();
    }

    // ======== P8: softmax over T; record attn ========
    {
      float val = (tid < Tt) ? sScore[tid] : -3.0e38f;
      float m = val;
      #pragma unroll
      for (int off = 32; off >= 1; off >>= 1) m = fmaxf(m, __shfl_xor(m, off));
      if (lane == 0) sRed[wid] = m;
      __syncthreads();
      float bm = sRed[0];
      #pragma unroll
      for (int w = 1; w < 16; ++w) bm = fmaxf(bm, sRed[w]);
      float e = (tid < Tt) ? __expf(val - bm) : 0.f;
      float ssum = e;
      #pragma unroll
      for (int off = 32; off >= 1; off >>= 1) ssum += __shfl_xor(ssum, off);
      __syncthreads();
      if (lane == 0) sRed[wid] = ssum;
      __syncthreads();
      float S = 0.f;
      #pragma unroll
      for (int w = 0; w < 16; ++w) S += sRed[w];
      if (tid < Tt) {
        float attn = e / S;
        sScore[tid] = attn;
        attn_out[((size_t)b * STEPS + t) * Tt + tid] = attn;
      }
      __syncthreads();
    }

    // ======== P9: ctx[e] = sum_tt attn[tt]*enc_feat[b,tt,e] ========
    {
      float4 acc = {0.f, 0.f, 0.f, 0.f};
      #pragma unroll 8
      for (int tt = t9a; tt < t9b; ++tt) {
        float a = sScore[tt];
        float4 f = *(const float4*)(fb9 + (size_t)tt * Ee);
        acc.x = fmaf(a, f.x, acc.x);
        acc.y = fmaf(a, f.y, acc.y);
        acc.z = fmaf(a, f.z, acc.z);
        acc.w = fmaf(a, f.w, acc.w);
      }
      *(float4*)&sTmp[tid * 4] = acc;
      __syncthreads();
      if (tid < 256) {
        float v = 0.f;
        #pragma unroll
        for (int s = 0; s < 16; ++s) v += sTmp[(s * 64 + (tid >> 2)) * 4 + (tid & 3)];
        sCtx[tid] = v;
        sIn[128 + tid] = v;
      }
      __syncthreads();
    }

    // ======== P10: raw = [h,ctx] @ W_out + b_out ========
    if (tid < 800) { float4 a = dotq<64, 400>(p10W, p10x); *(float4*)&sTmp[tid * 4] = a; }
    __syncthreads();
    if (tid < 400) {
      float v = bOut;
      #pragma unroll
      for (int s = 0; s < 8; ++s) v += sTmp[(s * 100 + (tid >> 2)) * 4 + (tid & 3)];
      sRaw[tid] = v;
    }
    __syncthreads();

    // ======== P11: pred = chunked softmax(raw, 5x80); record pred ========
    {
      if (wid < Rr) {
        int d0 = wid * 80 + lane;
        float v0 = sRaw[d0];
        float v1 = (lane < 16) ? sRaw[d0 + 64] : -3.0e38f;
        float m = fmaxf(v0, v1);
        #pragma unroll
        for (int off = 32; off >= 1; off >>= 1) m = fmaxf(m, __shfl_xor(m, off));
        float e0 = __expf(v0 - m);
        float e1 = (lane < 16) ? __expf(v1 - m) : 0.f;
        float s = e0 + e1;
        #pragma unroll
        for (int off = 32; off >= 1; off >>= 1) s += __shfl_xor(s, off);
        float inv = 1.0f / s;
        float p0 = e0 * inv;
        sPred[d0] = p0;
        pred_out[((size_t)b * STEPS + t) * Dd + d0] = p0;
        if (lane < 16) {
          float p1 = e1 * inv;
          sPred[d0 + 64] = p1;
          pred_out[((size_t)b * STEPS + t) * Dd + d0 + 64] = p1;
        }
      }
      __syncthreads();
    }
  }
}

// ---------------------------------------------------------------------------
extern "C" void kernel_launch(void* const* d_in, const int* in_sizes, int n_in,
                              void* d_out, int out_size, void* d_ws, size_t ws_size,
                              hipStream_t stream) {
  const float* enc_feat = (const float*)d_in[0];
  const float* W_p1  = (const float*)d_in[1];
  const float* b_p1  = (const float*)d_in[2];
  const float* W_p2  = (const float*)d_in[3];
  const float* b_p2  = (const float*)d_in[4];
  const float* W_ix  = (const float*)d_in[5];
  const float* W_ih  = (const float*)d_in[6];
  const float* b_ix  = (const float*)d_in[7];
  const float* b_ih  = (const float*)d_in[8];
  const float* W_dec = (const float*)d_in[9];
  const float* W_enc = (const float*)d_in[10];
  const float* b_attn= (const float*)d_in[11];
  const float* v_attn= (const float*)d_in[12];
  const float* W_out = (const float*)d_in[13];
  const float* b_out = (const float*)d_in[14];

  float* pred_out = (float*)d_out;                          // [64,500,400]
  float* attn_out = pred_out + (size_t)Bb * STEPS * Dd;     // [64,500,500]
  float* enc_proj = (float*)d_ws;                           // [64,500,128]

  k_encproj<<<dim3(Bb, 32), 512, 0, stream>>>(enc_feat, W_enc, enc_proj);
  k_decoder<<<Bb, 1024, 0, stream>>>(enc_feat, enc_proj,
                                     W_p1, b_p1, W_p2, b_p2,
                                     W_ix, W_ih, b_ix, b_ih,
                                     W_dec, b_attn, v_attn, W_out, b_out,
                                     pred_out, attn_out);
}

// Round 3
// 41889.771 us; speedup vs baseline: 2.1379x; 2.1379x over previous
//
#include <hip/hip_runtime.h>
#include <math.h>

// Problem constants
constexpr int Bb = 64, Tt = 500, Ee = 256, Aa = 128, Dd = 400;
constexpr int STEPS = 500, Rr = 5;

// d_ws layout (float offsets)
//   enc_proj : [64][500][128]
//   stage    : [64][2048]  per-row staging vectors
//   counters : [64][64] u32 (256B stride per row)
constexpr size_t WS_ENCPROJ_F = 0;
constexpr size_t WS_STAGE_F   = (size_t)Bb * Tt * Aa;          // 4,096,000
constexpr size_t WS_CNT_F     = WS_STAGE_F + (size_t)Bb * 2048;
constexpr int SG_L1 = 0, SG_H = 256, SG_SC = 512, SG_CTX = 1024, SG_RAW = 1280;
constexpr int SG_STRIDE = 2048;

// ---------------------------------------------------------------------------
// Pre-kernel: enc_proj[b,t,a] = sum_k enc_feat[b,t,k] * W_enc[k,a]
// ---------------------------------------------------------------------------
__global__ __launch_bounds__(512)
void k_encproj(const float* __restrict__ enc_feat,
               const float* __restrict__ W_enc,
               float* __restrict__ enc_proj) {
  __shared__ float sFeat[16][256];
  const int b = blockIdx.x, tg = blockIdx.y;
  const int t0 = tg * 16;
  const int tid = threadIdx.x;

  #pragma unroll
  for (int i = 0; i < 8; ++i) {
    int idx = tid + i * 512;
    int r = idx >> 8, c = idx & 255;
    int t = t0 + r;
    sFeat[r][c] = (t < Tt) ? enc_feat[((size_t)b * Tt + t) * Ee + c] : 0.0f;
  }
  __syncthreads();

  const int a = tid & 127, tl = tid >> 7;
  float acc0 = 0.f, acc1 = 0.f, acc2 = 0.f, acc3 = 0.f;
  #pragma unroll 4
  for (int k = 0; k < Ee; ++k) {
    float w = W_enc[k * Aa + a];
    acc0 = fmaf(sFeat[tl][k],      w, acc0);
    acc1 = fmaf(sFeat[tl + 4][k],  w, acc1);
    acc2 = fmaf(sFeat[tl + 8][k],  w, acc2);
    acc3 = fmaf(sFeat[tl + 12][k], w, acc3);
  }
  float accs[4] = {acc0, acc1, acc2, acc3};
  #pragma unroll
  for (int i = 0; i < 4; ++i) {
    int t = t0 + tl + 4 * i;
    if (t < Tt) enc_proj[((size_t)b * Tt + t) * Aa + a] = accs[i];
  }
}

// ---------------------------------------------------------------------------
// Helpers
// ---------------------------------------------------------------------------
__device__ __forceinline__ float sigmoid_acc(float x) {
  float e = __expf(-x);
  return 1.0f / (1.0f + e);
}
__device__ __forceinline__ float tanh_acc(float x) {
  float cx = fminf(9.5f, fmaxf(-9.5f, x));
  float e = __expf(2.0f * cx);
  return (e - 1.0f) / (e + 1.0f);
}
__device__ __forceinline__ float tanh_fast(float x) {
  float cx = fminf(9.5f, fmaxf(-9.5f, x));
  float e = __expf(2.0f * cx);
  return (e - 1.0f) * __builtin_amdgcn_rcpf(e + 1.0f);
}

// Per-row 4-block sync: monotone epoch counter, release add + relaxed spin +
// acquire fence. Correct at device scope regardless of XCD placement.
__device__ __forceinline__ void rowsync(unsigned* __restrict__ cnt, int tid, int& target) {
  __syncthreads();  // compiler drains vmem before s_barrier -> stores are in L2
  target += 4;
  if (tid == 0) {
    __hip_atomic_fetch_add(cnt, 1u, __ATOMIC_RELEASE, __HIP_MEMORY_SCOPE_AGENT);
    while (__hip_atomic_load(cnt, __ATOMIC_RELAXED, __HIP_MEMORY_SCOPE_AGENT) < (unsigned)target) { }
    __threadfence();  // acquire: invalidate stale L1/L2 before consumers read
  }
  __syncthreads();
}

// ---------------------------------------------------------------------------
// Persistent decoder: 256 blocks (4 per batch row) x 512 threads.
// Block bid: r = bid & 63 (row), j = bid >> 6 (column-slice part).
// ---------------------------------------------------------------------------
__global__ __launch_bounds__(512)
void k_decoder(const float* __restrict__ enc_feat,
               const float* __restrict__ enc_proj,
               float* __restrict__ stage, unsigned* __restrict__ cntbase,
               const float* __restrict__ W_p1, const float* __restrict__ b_p1,
               const float* __restrict__ W_p2, const float* __restrict__ b_p2,
               const float* __restrict__ W_ix, const float* __restrict__ W_ih,
               const float* __restrict__ b_ix, const float* __restrict__ b_ih,
               const float* __restrict__ W_dec, const float* __restrict__ b_attn,
               const float* __restrict__ v_attn,
               const float* __restrict__ W_out, const float* __restrict__ b_out,
               float* __restrict__ pred_out, float* __restrict__ attn_out) {
  __shared__ __align__(16) float sPred[400];
  __shared__ __align__(16) float sIn[384];    // [x(128) | ctx_prev(256)]
  __shared__ __align__(16) float sL1[256];
  __shared__ __align__(16) float sCat[512];   // [h(256) | ctx(256)]
  __shared__ __align__(16) float sSd[128];
  __shared__ __align__(16) float sScore[512];
  __shared__ __align__(16) float sRaw[400];
  __shared__ __align__(16) float sTmp[2048];
  __shared__ float sRed[8];

  float* sH = sCat;  // alias: h = sCat[0:256]

  const int bid = blockIdx.x;
  const int r = bid & 63, j = bid >> 6;
  const int tid = threadIdx.x;
  const int lane = tid & 63, wid = tid >> 6;
  const int l4 = tid & 3;

  float* stg = stage + (size_t)r * SG_STRIDE;
  unsigned* cnt = cntbase + r * 64;
  int target = 0;

  // ---- init local state
  for (int i = tid; i < 400; i += 512) sPred[i] = 0.f;
  if (tid < 256) { sH[tid] = 0.f; sIn[128 + tid] = 0.f; }

  // ---- preload constants
  float4 vq[8];
  #pragma unroll
  for (int i = 0; i < 8; ++i) vq[i] = *(const float4*)(v_attn + 4 * (l4 + 4 * i));

  float bP1 = 0.f, bR = 0.f, bZ = 0.f, bIN = 0.f, bHN = 0.f;
  if (tid < 64) {
    int c = 64 * j + tid;
    bP1 = b_p1[c];
    bR  = b_ix[c]       + b_ih[c];
    bZ  = b_ix[256 + c] + b_ih[256 + c];
    bIN = b_ix[512 + c];
    bHN = b_ih[512 + c];
  }
  float bP2 = 0.f, bAt = 0.f;
  if (tid < 128) { bP2 = b_p2[tid]; bAt = b_attn[tid]; }
  float bOut = 0.f;
  if (tid < 100) bOut = b_out[100 * j + tid];

  // ---- per-thread GEMV geometry (constant across steps)
  // P1 (split): 16 quads (64 cols) x 32 k-slices over K=400
  const int p1q = tid & 15, p1s = tid >> 4;
  const int p1k0 = 12 * p1s + min(p1s, 16);
  const int p1k1 = p1k0 + ((p1s < 16) ? 13 : 12);
  const float* p1W = W_p1 + (64 * j + 4 * p1q) + (size_t)p1k0 * 256;
  // P2 (replicated): 32 quads (128 cols) x 16 slices, KS=16, K=256
  const int p2q = tid & 31, p2s = tid >> 5;
  const float* p2W = W_p2 + 4 * p2q + (size_t)(16 * p2s) * 128;
  // P6 (replicated): same geometry on W_dec
  const float* p6W = W_dec + 4 * p2q + (size_t)(16 * p2s) * 128;
  // GRU (split): i-region 288 thr (48 quads x 6 slices, K=384, KS=64)
  //              h-region 192 thr (48 quads x 4 slices, K=256, KS=64)
  const float* gW = W_ix;
  const float* gx = sIn;
  if (tid < 288) {
    int q = tid % 48, s = tid / 48;
    int g = q >> 4, lq = q & 15;
    gW = W_ix + (size_t)(s * 64) * 768 + (g * 256 + 64 * j + 4 * lq);
    gx = sIn + s * 64;
  } else if (tid < 480) {
    int t2 = tid - 288, q = t2 % 48, s = t2 / 48;
    int g = q >> 4, lq = q & 15;
    gW = W_ih + (size_t)(s * 64) * 768 + (g * 256 + 64 * j + 4 * lq);
    gx = sH + s * 64;
  }
  const bool gAct = tid < 480;
  // P10 (split): 25 quads (100 cols) x 20 k-slices over K=512
  const int p10q = tid % 25, p10s = tid / 25;
  const int p10k0 = 25 * p10s + min(p10s, 12);
  const int p10k1 = p10k0 + ((p10s < 12) ? 26 : 25);
  const float* p10W = W_out + (100 * j + 4 * p10q) + (size_t)p10k0 * 400;
  // P9 (split): 16 e-quads x 32 t-slices of 16
  const int e9q = tid & 15, t9s = tid >> 4;
  const int t9a = t9s * 16;
  const int t9b = (t9a + 16 < Tt) ? t9a + 16 : Tt;
  const float* fb9 = enc_feat + (size_t)r * Tt * Ee + (64 * j + 4 * e9q);
  // P7 (split): 4 lanes per tt, 125 tt's
  const int tt7 = tid >> 2;
  const float* ep7 = enc_proj + ((size_t)r * Tt + (125 * j + tt7)) * Aa;

  __syncthreads();

  for (int t = 0; t < STEPS; ++t) {
    // ======== P1 (split): l1 = relu(pred @ W_p1 + b_p1), cols [64j,64j+64) ==
    {
      float4 acc = {0.f, 0.f, 0.f, 0.f};
      const float* W = p1W;
      #pragma unroll 8
      for (int k = p1k0; k < p1k1; ++k, W += 256) {
        float xv = sPred[k];
        float4 w = *(const float4*)W;
        acc.x = fmaf(xv, w.x, acc.x); acc.y = fmaf(xv, w.y, acc.y);
        acc.z = fmaf(xv, w.z, acc.z); acc.w = fmaf(xv, w.w, acc.w);
      }
      *(float4*)&sTmp[tid * 4] = acc;
    }
    __syncthreads();
    if (tid < 64) {
      float v = bP1;
      #pragma unroll
      for (int s = 0; s < 32; ++s) v += sTmp[(16 * s + (tid >> 2)) * 4 + (tid & 3)];
      stg[SG_L1 + 64 * j + tid] = fmaxf(v, 0.f);
    }
    rowsync(cnt, tid, target);
    if (tid < 256) sL1[tid] = stg[SG_L1 + tid];
    __syncthreads();

    // ======== P2 (replicated): x = relu(l1 @ W_p2 + b_p2) -> sIn[0:128] ====
    {
      float4 acc = {0.f, 0.f, 0.f, 0.f};
      const float* W = p2W;
      const float* xp = sL1 + 16 * p2s;
      #pragma unroll 8
      for (int k = 0; k < 16; ++k, W += 128) {
        float xv = xp[k];
        float4 w = *(const float4*)W;
        acc.x = fmaf(xv, w.x, acc.x); acc.y = fmaf(xv, w.y, acc.y);
        acc.z = fmaf(xv, w.z, acc.z); acc.w = fmaf(xv, w.w, acc.w);
      }
      *(float4*)&sTmp[tid * 4] = acc;
    }
    __syncthreads();
    if (tid < 128) {
      float v = bP2;
      #pragma unroll
      for (int s = 0; s < 16; ++s) v += sTmp[(32 * s + (tid >> 2)) * 4 + (tid & 3)];
      sIn[tid] = fmaxf(v, 0.f);
    }
    __syncthreads();

    // ======== GRU (split): 6 gate-slices fused, h cols [64j,64j+64) ========
    if (gAct) {
      float4 acc = {0.f, 0.f, 0.f, 0.f};
      const float* W = gW;
      const float* xp = gx;
      #pragma unroll 8
      for (int k = 0; k < 64; ++k, W += 768) {
        float xv = xp[k];
        float4 w = *(const float4*)W;
        acc.x = fmaf(xv, w.x, acc.x); acc.y = fmaf(xv, w.y, acc.y);
        acc.z = fmaf(xv, w.z, acc.z); acc.w = fmaf(xv, w.w, acc.w);
      }
      *(float4*)&sTmp[tid * 4] = acc;
    }
    __syncthreads();
    if (tid < 64) {
      const int cq = tid >> 2, ce = tid & 3;
      float cr = bR, cz = bZ, vin = bIN, vhn = bHN;
      #pragma unroll
      for (int s = 0; s < 6; ++s) {
        cr  += sTmp[(48 * s +      cq) * 4 + ce];
        cz  += sTmp[(48 * s + 16 + cq) * 4 + ce];
        vin += sTmp[(48 * s + 32 + cq) * 4 + ce];
      }
      #pragma unroll
      for (int s = 0; s < 4; ++s) {
        cr  += sTmp[(288 + 48 * s +      cq) * 4 + ce];
        cz  += sTmp[(288 + 48 * s + 16 + cq) * 4 + ce];
        vhn += sTmp[(288 + 48 * s + 32 + cq) * 4 + ce];
      }
      float rg = sigmoid_acc(cr);
      float zg = sigmoid_acc(cz);
      float n  = tanh_acc(vin + rg * vhn);
      stg[SG_H + 64 * j + tid] = (1.f - zg) * n + zg * sH[64 * j + tid];
    }
    rowsync(cnt, tid, target);
    if (tid < 256) sH[tid] = stg[SG_H + tid];
    __syncthreads();

    // ======== P6 (replicated): sd = h @ W_dec + b_attn -> sSd ==============
    {
      float4 acc = {0.f, 0.f, 0.f, 0.f};
      const float* W = p6W;
      const float* xp = sH + 16 * p2s;
      #pragma unroll 8
      for (int k = 0; k < 16; ++k, W += 128) {
        float xv = xp[k];
        float4 w = *(const float4*)W;
        acc.x = fmaf(xv, w.x, acc.x); acc.y = fmaf(xv, w.y, acc.y);
        acc.z = fmaf(xv, w.z, acc.z); acc.w = fmaf(xv, w.w, acc.w);
      }
      *(float4*)&sTmp[tid * 4] = acc;
    }
    __syncthreads();
    if (tid < 128) {
      float v = bAt;
      #pragma unroll
      for (int s = 0; s < 16; ++s) v += sTmp[(32 * s + (tid >> 2)) * 4 + (tid & 3)];
      sSd[tid] = v;
    }
    __syncthreads();

    // ======== P7 (split): scores for tt in [125j, 125j+125) ================
    {
      float4 sdq[8];
      #pragma unroll
      for (int i = 0; i < 8; ++i) sdq[i] = *(const float4*)(sSd + 4 * (l4 + 4 * i));
      float acc = 0.f;
      if (tt7 < 125) {
        #pragma unroll
        for (int i = 0; i < 8; ++i) {
          float4 e4 = ((const float4*)ep7)[l4 + 4 * i];
          acc = fmaf(vq[i].x, tanh_fast(e4.x + sdq[i].x), acc);
          acc = fmaf(vq[i].y, tanh_fast(e4.y + sdq[i].y), acc);
          acc = fmaf(vq[i].z, tanh_fast(e4.z + sdq[i].z), acc);
          acc = fmaf(vq[i].w, tanh_fast(e4.w + sdq[i].w), acc);
        }
      }
      acc += __shfl_xor(acc, 1);
      acc += __shfl_xor(acc, 2);
      if (l4 == 0 && tt7 < 125) stg[SG_SC + 125 * j + tt7] = acc;
    }
    rowsync(cnt, tid, target);
    if (tid < Tt) sScore[tid] = stg[SG_SC + tid];
    __syncthreads();

    // ======== P8 (replicated): softmax over T; owner quarter writes ========
    {
      float val = (tid < Tt) ? sScore[tid] : -3.0e38f;
      float m = val;
      #pragma unroll
      for (int off = 32; off >= 1; off >>= 1) m = fmaxf(m, __shfl_xor(m, off));
      if (lane == 0) sRed[wid] = m;
      __syncthreads();
      float bm = sRed[0];
      #pragma unroll
      for (int w = 1; w < 8; ++w) bm = fmaxf(bm, sRed[w]);
      float e = (tid < Tt) ? __expf(val - bm) : 0.f;
      float ssum = e;
      #pragma unroll
      for (int off = 32; off >= 1; off >>= 1) ssum += __shfl_xor(ssum, off);
      __syncthreads();
      if (lane == 0) sRed[wid] = ssum;
      __syncthreads();
      float S = 0.f;
      #pragma unroll
      for (int w = 0; w < 8; ++w) S += sRed[w];
      if (tid < Tt) {
        float attn = e / S;
        sScore[tid] = attn;
        if (tid >= 125 * j && tid < 125 * (j + 1))
          attn_out[((size_t)r * STEPS + t) * Tt + tid] = attn;
      }
      __syncthreads();
    }

    // ======== P9 (split): ctx[e] for e in [64j,64j+64) =====================
    {
      float4 acc = {0.f, 0.f, 0.f, 0.f};
      #pragma unroll 8
      for (int tt = t9a; tt < t9b; ++tt) {
        float a = sScore[tt];
        float4 f = *(const float4*)(fb9 + (size_t)tt * Ee);
        acc.x = fmaf(a, f.x, acc.x); acc.y = fmaf(a, f.y, acc.y);
        acc.z = fmaf(a, f.z, acc.z); acc.w = fmaf(a, f.w, acc.w);
      }
      *(float4*)&sTmp[tid * 4] = acc;
      __syncthreads();
      if (tid < 64) {
        float v = 0.f;
        #pragma unroll
        for (int s = 0; s < 32; ++s) v += sTmp[(16 * s + (tid >> 2)) * 4 + (tid & 3)];
        stg[SG_CTX + 64 * j + tid] = v;
      }
      rowsync(cnt, tid, target);
      if (tid < 256) {
        float v = stg[SG_CTX + tid];
        sIn[128 + tid] = v;
        sCat[256 + tid] = v;
      }
      __syncthreads();
    }

    // ======== P10 (split): raw cols [100j,100j+100) ========================
    if (tid < 500) {
      float4 acc = {0.f, 0.f, 0.f, 0.f};
      const float* W = p10W;
      #pragma unroll 8
      for (int k = p10k0; k < p10k1; ++k, W += 400) {
        float xv = sCat[k];
        float4 w = *(const float4*)W;
        acc.x = fmaf(xv, w.x, acc.x); acc.y = fmaf(xv, w.y, acc.y);
        acc.z = fmaf(xv, w.z, acc.z); acc.w = fmaf(xv, w.w, acc.w);
      }
      *(float4*)&sTmp[tid * 4] = acc;
    }
    __syncthreads();
    if (tid < 100) {
      float v = bOut;
      #pragma unroll
      for (int s = 0; s < 20; ++s) v += sTmp[(25 * s + (tid >> 2)) * 4 + (tid & 3)];
      stg[SG_RAW + 100 * j + tid] = v;
    }
    rowsync(cnt, tid, target);
    if (tid < 400) sRaw[tid] = stg[SG_RAW + tid];
    __syncthreads();

    // ======== P11 (replicated): chunked softmax -> sPred; j==0 writes ======
    {
      if (wid < Rr) {
        int d0 = wid * 80 + lane;
        float v0 = sRaw[d0];
        float v1 = (lane < 16) ? sRaw[d0 + 64] : -3.0e38f;
        float m = fmaxf(v0, v1);
        #pragma unroll
        for (int off = 32; off >= 1; off >>= 1) m = fmaxf(m, __shfl_xor(m, off));
        float e0 = __expf(v0 - m);
        float e1 = (lane < 16) ? __expf(v1 - m) : 0.f;
        float s = e0 + e1;
        #pragma unroll
        for (int off = 32; off >= 1; off >>= 1) s += __shfl_xor(s, off);
        float inv = 1.0f / s;
        float p0 = e0 * inv;
        sPred[d0] = p0;
        if (j == 0) pred_out[((size_t)r * STEPS + t) * Dd + d0] = p0;
        if (lane < 16) {
          float p1 = e1 * inv;
          sPred[d0 + 64] = p1;
          if (j == 0) pred_out[((size_t)r * STEPS + t) * Dd + d0 + 64] = p1;
        }
      }
      __syncthreads();
    }
  }
}

// ---------------------------------------------------------------------------
extern "C" void kernel_launch(void* const* d_in, const int* in_sizes, int n_in,
                              void* d_out, int out_size, void* d_ws, size_t ws_size,
                              hipStream_t stream) {
  const float* enc_feat = (const float*)d_in[0];
  const float* W_p1  = (const float*)d_in[1];
  const float* b_p1  = (const float*)d_in[2];
  const float* W_p2  = (const float*)d_in[3];
  const float* b_p2  = (const float*)d_in[4];
  const float* W_ix  = (const float*)d_in[5];
  const float* W_ih  = (const float*)d_in[6];
  const float* b_ix  = (const float*)d_in[7];
  const float* b_ih  = (const float*)d_in[8];
  const float* W_dec = (const float*)d_in[9];
  const float* W_enc = (const float*)d_in[10];
  const float* b_attn= (const float*)d_in[11];
  const float* v_attn= (const float*)d_in[12];
  const float* W_out = (const float*)d_in[13];
  const float* b_out = (const float*)d_in[14];

  float* pred_out = (float*)d_out;                          // [64,500,400]
  float* attn_out = pred_out + (size_t)Bb * STEPS * Dd;     // [64,500,500]

  float* enc_proj = (float*)d_ws + WS_ENCPROJ_F;
  float* stage    = (float*)d_ws + WS_STAGE_F;
  unsigned* cnt   = (unsigned*)((float*)d_ws + WS_CNT_F);

  hipMemsetAsync(cnt, 0, 64 * 64 * sizeof(unsigned), stream);
  k_encproj<<<dim3(Bb, 32), 512, 0, stream>>>(enc_feat, W_enc, enc_proj);

  void* args[] = {
    (void*)&enc_feat, (void*)&enc_proj, (void*)&stage, (void*)&cnt,
    (void*)&W_p1, (void*)&b_p1, (void*)&W_p2, (void*)&b_p2,
    (void*)&W_ix, (void*)&W_ih, (void*)&b_ix, (void*)&b_ih,
    (void*)&W_dec, (void*)&b_attn, (void*)&v_attn,
    (void*)&W_out, (void*)&b_out, (void*)&pred_out, (void*)&attn_out
  };
  hipLaunchCooperativeKernel(reinterpret_cast<const void*>(k_decoder),
                             dim3(4 * Bb), dim3(512), args, 0, stream);
}